// Round 2
// baseline (219.658 us; speedup 1.0000x reference)
//
#include <hip/hip_runtime.h>

// Problem constants (match reference):
//   B=8192, S=200, E=8, H1=64, H2=32
//   att_in = [q, h, q-h, q*h]  (32)  -> relu(@W1[32,64]+b1) -> relu(@W2[64,32]+b2)
//   score = @W3[32,1]+b3 ; masked by s < len[b] ; out[b,:] = sum_s score*hist[b,s,:]
#define BB 8192
#define SS 200
#define EE 8
#define HH1 64
#define HH2 32

// ---- prep: transpose W1 [32,64] -> W1T [64,32] in workspace so the per-i
// weight "column" becomes a contiguous 128B row (scalar-cache friendly) ----
__global__ void w1_transpose_kernel(const float* __restrict__ W1,
                                    float* __restrict__ W1T) {
    int idx = blockIdx.x * blockDim.x + threadIdx.x;   // 0..2047
    if (idx < 32 * 64) {
        int k = idx >> 6;          // row in W1 (0..31)
        int i = idx & 63;          // col in W1 (0..63)
        W1T[i * 32 + k] = W1[idx];
    }
}

// ---- main: one block per batch row b; thread t handles position s=t ----
__global__ __launch_bounds__(256)
void din_pool_kernel(const float* __restrict__ query,      // [B,1,E]
                     const float* __restrict__ hist,       // [B,S,E]
                     const int* __restrict__ hlen,         // [B,1] int32 (JAX demotes int64)
                     const float* __restrict__ W1T,        // [64,32] (ws)
                     const float* __restrict__ b1,         // [64]
                     const float* __restrict__ W2,         // [64,32]
                     const float* __restrict__ b2,         // [32]
                     const float* __restrict__ W3,         // [32]
                     const float* __restrict__ b3,         // [1]
                     float* __restrict__ out)              // [B,1,E]
{
    const int b = blockIdx.x;
    const int t = threadIdx.x;

    __shared__ float red[256][9];   // stride 9 floats -> conflict-free tree

    const int len = hlen[b];

    float contrib[EE];
#pragma unroll
    for (int e = 0; e < EE; ++e) contrib[e] = 0.0f;

    if (t < SS) {
        // q (uniform per block) and this thread's history row (coalesced)
        const float4* qp = reinterpret_cast<const float4*>(query + (size_t)b * EE);
        const float4 q0 = qp[0], q1 = qp[1];
        const float4* hp = reinterpret_cast<const float4*>(hist + ((size_t)b * SS + t) * EE);
        const float4 h0 = hp[0], h1 = hp[1];

        float q[EE], h[EE];
        q[0]=q0.x; q[1]=q0.y; q[2]=q0.z; q[3]=q0.w;
        q[4]=q1.x; q[5]=q1.y; q[6]=q1.z; q[7]=q1.w;
        h[0]=h0.x; h[1]=h0.y; h[2]=h0.z; h[3]=h0.w;
        h[4]=h1.x; h[5]=h1.y; h[6]=h1.z; h[7]=h1.w;

        // att_in = [q, h, q-h, q*h]  -- statically indexed only
        float att[32];
#pragma unroll
        for (int e = 0; e < EE; ++e) {
            att[e]      = q[e];
            att[8 + e]  = h[e];
            att[16 + e] = q[e] - h[e];
            att[24 + e] = q[e] * h[e];
        }

        // h2 accumulators (MLP2 scatter form so h1 never needs an array)
        float h2[HH2];
#pragma unroll
        for (int j = 0; j < HH2; ++j) h2[j] = b2[j];

#pragma unroll 4
        for (int i = 0; i < HH1; ++i) {
            const float* __restrict__ w1c = W1T + i * 32;  // contiguous col of W1
            float a = b1[i];
#pragma unroll
            for (int k = 0; k < 32; ++k) a = fmaf(att[k], w1c[k], a);
            a = fmaxf(a, 0.0f);                            // relu(h1_i)
            const float* __restrict__ w2r = W2 + i * 32;   // row i of W2
#pragma unroll
            for (int j = 0; j < HH2; ++j) h2[j] = fmaf(a, w2r[j], h2[j]);
        }

        float sc = b3[0];
#pragma unroll
        for (int j = 0; j < HH2; ++j) sc = fmaf(fmaxf(h2[j], 0.0f), W3[j], sc);

        if (t < len) {
#pragma unroll
            for (int e = 0; e < EE; ++e) contrib[e] = sc * h[e];
        }
    }

    // block reduction: out[b,e] = sum_t contrib[t][e]
#pragma unroll
    for (int e = 0; e < EE; ++e) red[t][e] = contrib[e];
    __syncthreads();
    for (int off = 128; off > 0; off >>= 1) {
        if (t < off) {
#pragma unroll
            for (int e = 0; e < EE; ++e) red[t][e] += red[t + off][e];
        }
        __syncthreads();
    }
    if (t < EE) out[(size_t)b * EE + t] = red[0][t];
}

extern "C" void kernel_launch(void* const* d_in, const int* in_sizes, int n_in,
                              void* d_out, int out_size, void* d_ws, size_t ws_size,
                              hipStream_t stream) {
    const float* query = (const float*)d_in[0];
    const float* hist  = (const float*)d_in[1];
    const int*   hlen  = (const int*)d_in[2];
    const float* W1    = (const float*)d_in[3];
    const float* b1    = (const float*)d_in[4];
    const float* W2    = (const float*)d_in[5];
    const float* b2    = (const float*)d_in[6];
    const float* W3    = (const float*)d_in[7];
    const float* b3    = (const float*)d_in[8];
    float*       out   = (float*)d_out;
    float*       W1T   = (float*)d_ws;   // 2048 floats = 8 KiB

    w1_transpose_kernel<<<8, 256, 0, stream>>>(W1, W1T);
    din_pool_kernel<<<BB, 256, 0, stream>>>(query, hist, hlen, W1T, b1, W2, b2,
                                            W3, b3, out);
}

// Round 4
// 88.423 us; speedup vs baseline: 2.4842x; 2.4842x over previous
//
#include <hip/hip_runtime.h>

// B=8192, S=200, E=8, H1=64, H2=32
// att_in = [q, h, q-h, q*h] (32) -> relu(@W1[32,64]+b1) -> relu(@W2[64,32]+b2)
// score = @W3[32,1]+b3 ; mask s<len ; out[b,:] = sum_s score*hist[b,s,:]
#define BB 8192
#define SS 200

typedef __attribute__((ext_vector_type(8))) short short8;   // bf16x8 MFMA frag
typedef __attribute__((ext_vector_type(4))) float f32x4;    // fp32x4 MFMA acc

__device__ __forceinline__ unsigned short f2bf(float f) {
    union { float f; unsigned int u; } v; v.f = f;
    unsigned int r = v.u + 0x7FFFu + ((v.u >> 16) & 1u);    // RNE
    return (unsigned short)(r >> 16);
}

// ---- prep: pack W1 [32,64] and W2 [64,32] into per-lane bf16 B-fragments ----
// B-frag layout for mfma_f32_16x16x32_bf16: lane l holds B[k = 8*(l>>4)+j][col = l&15]
// wsW1: [ntile n=0..3][lane 0..63][j=0..7]   (W1 cols 16n+c)
// wsW2: [kc=0..1][n=0..1][lane][j]           (W2 rows 32kc+8g+j, cols 16n+c)
__global__ void prep_kernel(const float* __restrict__ W1, const float* __restrict__ W2,
                            unsigned short* __restrict__ wsW1,
                            unsigned short* __restrict__ wsW2) {
    int t = threadIdx.x;             // 0..255
    int l = t & 63;
    int g = l >> 4, c = l & 15;
    {
        int n = t >> 6;              // 0..3
#pragma unroll
        for (int j = 0; j < 8; ++j)
            wsW1[(n * 64 + l) * 8 + j] = f2bf(W1[(8 * g + j) * 64 + 16 * n + c]);
    }
    {
        int kc = t >> 7, n = (t >> 6) & 1;
#pragma unroll
        for (int j = 0; j < 8; ++j)
            wsW2[((kc * 2 + n) * 64 + l) * 8 + j] = f2bf(W2[(32 * kc + 8 * g + j) * 32 + 16 * n + c]);
    }
}

// ---- main: one block per batch row; 4 waves; wave handles 16-position tiles ----
__global__ __launch_bounds__(256)
void din_mfma_kernel(const float* __restrict__ query,       // [B,1,8]
                     const float* __restrict__ hist,        // [B,200,8]
                     const int* __restrict__ hlen,          // [B] int32
                     const unsigned short* __restrict__ wsW1,
                     const unsigned short* __restrict__ wsW2,
                     const float* __restrict__ b1,          // [64]
                     const float* __restrict__ b2,          // [32]
                     const float* __restrict__ W3,          // [32]
                     const float* __restrict__ b3,          // [1]
                     float* __restrict__ out)               // [B,1,8]
{
    const int b    = blockIdx.x;
    const int tid  = threadIdx.x;
    const int wave = tid >> 6;
    const int l    = tid & 63;
    const int g    = l >> 4;     // lane group = k-block
    const int c    = l & 15;     // row (A/M) or col (B/N / D col)

    __shared__ alignas(16) unsigned short h1buf[4][1024];   // per-wave 16x64 bf16, XOR-swizzled
    __shared__ alignas(16) float outbuf[4][8];

    const int len = hlen[b];

    // ---- one-time per-block loads ----
    const float4* qp = reinterpret_cast<const float4*>(query + (size_t)b * 8);
    float4 qa = qp[0], qb = qp[1];
    float q[8] = {qa.x, qa.y, qa.z, qa.w, qb.x, qb.y, qb.z, qb.w};

    short8 w1f[4];
#pragma unroll
    for (int n = 0; n < 4; ++n)
        w1f[n] = *reinterpret_cast<const short8*>(wsW1 + (n * 64 + l) * 8);
    short8 w2f[2][2];
#pragma unroll
    for (int kc = 0; kc < 2; ++kc)
#pragma unroll
        for (int n = 0; n < 2; ++n)
            w2f[kc][n] = *reinterpret_cast<const short8*>(wsW2 + ((kc * 2 + n) * 64 + l) * 8);

    float b1v[4];
#pragma unroll
    for (int n = 0; n < 4; ++n) b1v[n] = b1[16 * n + c];
    float b2v[2], W3v[2];
#pragma unroll
    for (int n = 0; n < 2; ++n) { b2v[n] = b2[16 * n + c]; W3v[n] = W3[16 * n + c]; }
    const float b3s = b3[0];

    float accO[8];
#pragma unroll
    for (int e = 0; e < 8; ++e) accO[e] = 0.0f;

    // ---- tile loop: wave w handles tiles w, w+4, w+8, ... (13 tiles total) ----
    for (int t = wave; 16 * t < SS; t += 4) {
        const int s0 = 16 * t;
        const int sl = min(s0 + c, SS - 1);     // clamp overhang (masked later)
        const float4* hp = reinterpret_cast<const float4*>(hist + ((size_t)b * SS + sl) * 8);
        float4 ha = hp[0], hb = hp[1];
        float h[8] = {ha.x, ha.y, ha.z, ha.w, hb.x, hb.y, hb.z, hb.w};

        // A-frag: lane row = c, k = 8g+j; k-blocks = [q, h, q-h, q*h]
        short8 af;
#pragma unroll
        for (int j = 0; j < 8; ++j) {
            float v = (g == 0) ? q[j]
                    : (g == 1) ? h[j]
                    : (g == 2) ? (q[j] - h[j])
                               : (q[j] * h[j]);
            af[j] = (short)f2bf(v);
        }

        // ---- stage 1: h1[16,64] = relu(att @ W1 + b1) ----
        f32x4 acc1[4];
#pragma unroll
        for (int n = 0; n < 4; ++n) {
            acc1[n] = (f32x4){b1v[n], b1v[n], b1v[n], b1v[n]};
            acc1[n] = __builtin_amdgcn_mfma_f32_16x16x32_bf16(af, w1f[n], acc1[n], 0, 0, 0);
        }

        // D-layout (row=4g+r, col=16n+c) -> LDS [row][col] with byte-XOR swizzle
        // ushort idx = row*64 + (col ^ ((row&7)<<3))  (byte ^ ((row&7)<<4))
#pragma unroll
        for (int n = 0; n < 4; ++n)
#pragma unroll
            for (int r = 0; r < 4; ++r) {
                float v = fmaxf(acc1[n][r], 0.0f);
                int row = 4 * g + r, col = 16 * n + c;
                h1buf[wave][row * 64 + (col ^ ((row & 7) << 3))] = f2bf(v);
            }

        // wave-local cross-lane LDS dependency: drain before reading
        asm volatile("s_waitcnt lgkmcnt(0)" ::: "memory");

        // A-frag of h1: lane row = c, k = 32kc + 8g + j  (aligned ds_read_b128)
        short8 h1a[2];
#pragma unroll
        for (int kc = 0; kc < 2; ++kc)
            h1a[kc] = *reinterpret_cast<const short8*>(
                &h1buf[wave][c * 64 + ((kc * 32 + 8 * g) ^ ((c & 7) << 3))]);

        // ---- stage 2: h2[16,32] = relu(h1 @ W2 + b2) ----
        f32x4 acc2[2];
#pragma unroll
        for (int n = 0; n < 2; ++n) {
            acc2[n] = (f32x4){b2v[n], b2v[n], b2v[n], b2v[n]};
            acc2[n] = __builtin_amdgcn_mfma_f32_16x16x32_bf16(h1a[0], w2f[0][n], acc2[n], 0, 0, 0);
            acc2[n] = __builtin_amdgcn_mfma_f32_16x16x32_bf16(h1a[1], w2f[1][n], acc2[n], 0, 0, 0);
        }

        // ---- stage 3: score[m] = relu(h2[m,:]) . W3 + b3, masked ----
        float p[4];
#pragma unroll
        for (int r = 0; r < 4; ++r)
            p[r] = fmaxf(acc2[0][r], 0.0f) * W3v[0] + fmaxf(acc2[1][r], 0.0f) * W3v[1];

        // sum over the 16 cols (lanes within group)
#pragma unroll
        for (int m = 1; m < 16; m <<= 1)
#pragma unroll
            for (int r = 0; r < 4; ++r)
                p[r] += __shfl_xor(p[r], m, 64);

#pragma unroll
        for (int r = 0; r < 4; ++r) {
            int srow = s0 + 4 * g + r;
            p[r] = (srow < len) ? (p[r] + b3s) : 0.0f;
        }

        // redistribute: this lane needs score of position s0+c  (group c>>2, reg c&3)
        const int src = (c >> 2) << 4;
        float sv0 = __shfl(p[0], src, 64);
        float sv1 = __shfl(p[1], src, 64);
        float sv2 = __shfl(p[2], src, 64);
        float sv3 = __shfl(p[3], src, 64);
        float sc = (c & 2) ? ((c & 1) ? sv3 : sv2) : ((c & 1) ? sv1 : sv0);

        // ---- pooling accumulate (fp32 hist already in registers) ----
#pragma unroll
        for (int e = 0; e < 8; ++e) accO[e] = fmaf(sc, h[e], accO[e]);
    }

    // reduce over the 16 rows-per-group (groups hold identical copies: masks < 16 only!)
#pragma unroll
    for (int m = 1; m < 16; m <<= 1)
#pragma unroll
        for (int e = 0; e < 8; ++e) accO[e] += __shfl_xor(accO[e], m, 64);

    if (l == 0) {
        *reinterpret_cast<float4*>(&outbuf[wave][0]) = make_float4(accO[0], accO[1], accO[2], accO[3]);
        *reinterpret_cast<float4*>(&outbuf[wave][4]) = make_float4(accO[4], accO[5], accO[6], accO[7]);
    }
    __syncthreads();
    if (tid < 8) {
        out[(size_t)b * 8 + tid] =
            outbuf[0][tid] + outbuf[1][tid] + outbuf[2][tid] + outbuf[3][tid];
    }
}

extern "C" void kernel_launch(void* const* d_in, const int* in_sizes, int n_in,
                              void* d_out, int out_size, void* d_ws, size_t ws_size,
                              hipStream_t stream) {
    const float* query = (const float*)d_in[0];
    const float* hist  = (const float*)d_in[1];
    const int*   hlen  = (const int*)d_in[2];
    const float* W1    = (const float*)d_in[3];
    const float* b1    = (const float*)d_in[4];
    const float* W2    = (const float*)d_in[5];
    const float* b2    = (const float*)d_in[6];
    const float* W3    = (const float*)d_in[7];
    const float* b3    = (const float*)d_in[8];
    float*       out   = (float*)d_out;

    unsigned short* wsW1 = (unsigned short*)d_ws;          // 4KB
    unsigned short* wsW2 = wsW1 + 4 * 64 * 8;              // 4KB

    prep_kernel<<<1, 256, 0, stream>>>(W1, W2, wsW1, wsW2);
    din_mfma_kernel<<<BB, 256, 0, stream>>>(query, hist, hlen, wsW1, wsW2,
                                            b1, b2, W3, b3, out);
}

// Round 5
// 50.605 us; speedup vs baseline: 4.3406x; 1.7473x over previous
//
#include <hip/hip_runtime.h>
#include <hip/hip_bf16.h>

// B=8192, S=200, E=8, H1=64, H2=32
// att_in = [q, h, q-h, q*h] (32) -> relu(@W1[32,64]+b1) -> relu(@W2[64,32]+b2)
// score = @W3[32,1]+b3 ; mask s<len ; out[b,:] = sum_s score*hist[b,s,:]
// This version computes the TRANSPOSED chain: h1^T = W1^T att^T, h2^T = W2^T relu(h1)^T
// so h2 of position c lands in the lanes owning position c (no redistribution).
#define BB 8192
#define SS 200

typedef __attribute__((ext_vector_type(8))) short short8;   // bf16x8 MFMA frag
typedef __attribute__((ext_vector_type(4))) float f32x4;    // fp32x4 MFMA acc

__device__ __forceinline__ unsigned short f2bf(float f) {
    union { float f; unsigned int u; } v; v.f = f;
    unsigned int r = v.u + 0x7FFFu + ((v.u >> 16) & 1u);    // RNE
    return (unsigned short)(r >> 16);
}
// pack 2 fp32 -> 1 u32 of 2 bf16 (compiler emits v_cvt_pk_bf16_f32)
__device__ __forceinline__ unsigned int packbf2(float a, float b) {
    union { __hip_bfloat162 h; unsigned int u; } v;
    v.h = __float22bfloat162_rn(make_float2(a, b));
    return v.u;
}

// ---- prep (unchanged from round 4; same packings serve as A- or B-frags) ----
// wsW1[(n*64+l)*8+j]          = W1[8g+j][16n+c]      (stage-1' A = W1^T tile n)
// wsW2[((kc*2+n)*64+l)*8+j]   = W2[32kc+8g+j][16n+c] (stage-2' A = W2^T tile n, k-chunk kc)
__global__ void prep_kernel(const float* __restrict__ W1, const float* __restrict__ W2,
                            unsigned short* __restrict__ wsW1,
                            unsigned short* __restrict__ wsW2) {
    int t = threadIdx.x;             // 0..255
    int l = t & 63;
    int g = l >> 4, c = l & 15;
    {
        int n = t >> 6;              // 0..3
#pragma unroll
        for (int j = 0; j < 8; ++j)
            wsW1[(n * 64 + l) * 8 + j] = f2bf(W1[(8 * g + j) * 64 + 16 * n + c]);
    }
    {
        int kc = t >> 7, n = (t >> 6) & 1;
#pragma unroll
        for (int j = 0; j < 8; ++j)
            wsW2[((kc * 2 + n) * 64 + l) * 8 + j] = f2bf(W2[(32 * kc + 8 * g + j) * 32 + 16 * n + c]);
    }
}

// ---- main: 4 waves/block, each wave owns one batch row ----
__global__ __launch_bounds__(256)
void din2_kernel(const float* __restrict__ query,       // [B,1,8]
                 const float* __restrict__ hist,        // [B,200,8]
                 const int* __restrict__ hlen,          // [B] int32
                 const unsigned short* __restrict__ wsW1,
                 const unsigned short* __restrict__ wsW2,
                 const float* __restrict__ b1,          // [64]
                 const float* __restrict__ b2,          // [32]
                 const float* __restrict__ W3,          // [32]
                 const float* __restrict__ b3,          // [1]
                 float* __restrict__ out)               // [B,1,8]
{
    const int tid  = threadIdx.x;
    const int wave = tid >> 6;
    const int l    = tid & 63;
    const int g    = l >> 4;     // k-block / j2-subrow group
    const int c    = l & 15;     // position-within-subtile (col)
    const int brow = blockIdx.x * 4 + wave;

    // per-wave h1 buffers: [2 subtile][16 pos][64 i] bf16, 16B-slot XOR swizzle
    __shared__ unsigned short lds[4][2][1024];

    const int len = hlen[brow];

    // ---- one-time per-row setup ----
    const float4* qp = reinterpret_cast<const float4*>(query + (size_t)brow * 8);
    float4 qa = qp[0], qb = qp[1];
    float q[8] = {qa.x, qa.y, qa.z, qa.w, qb.x, qb.y, qb.z, qb.w};

    // att value for this lane's k-block: v = alpha*q + (beta + gamma*q)*h
    const float alpha = (g == 0 || g == 2) ? 1.0f : 0.0f;
    const float beta  = (g == 1) ? 1.0f : ((g == 2) ? -1.0f : 0.0f);
    const float gamma = (g == 3) ? 1.0f : 0.0f;
    float aq[8], bcv[8];
#pragma unroll
    for (int j = 0; j < 8; ++j) { aq[j] = alpha * q[j]; bcv[j] = beta + gamma * q[j]; }

    short8 w1f[4];
#pragma unroll
    for (int n = 0; n < 4; ++n)
        w1f[n] = *reinterpret_cast<const short8*>(wsW1 + (n * 64 + l) * 8);
    short8 w2tf[2][2];
#pragma unroll
    for (int kc = 0; kc < 2; ++kc)
#pragma unroll
        for (int n2 = 0; n2 < 2; ++n2)
            w2tf[kc][n2] = *reinterpret_cast<const short8*>(wsW2 + ((kc * 2 + n2) * 64 + l) * 8);

    f32x4 b1c[4];
#pragma unroll
    for (int n = 0; n < 4; ++n)
        b1c[n] = *reinterpret_cast<const f32x4*>(b1 + 16 * n + 4 * g);
    f32x4 b2c[2], W3v[2];
#pragma unroll
    for (int n2 = 0; n2 < 2; ++n2) {
        b2c[n2] = *reinterpret_cast<const f32x4*>(b2 + 16 * n2 + 4 * g);
        W3v[n2] = *reinterpret_cast<const f32x4*>(W3 + 16 * n2 + 4 * g);
    }
    const float b3s = b3[0];

    // LDS offsets (ushort units within lds[wave][buf]):
    // write n: c*64 + ((2n + (g>>1)) ^ (c&7))*8 + (g&1)*4   (ds_write_b64)
    // read kc: c*64 + ((4kc + g) ^ (c&7))*8                 (ds_read_b128)
    int woff[4], roff[2];
#pragma unroll
    for (int n = 0; n < 4; ++n)
        woff[n] = c * 64 + (((2 * n + (g >> 1)) ^ (c & 7)) << 3) + ((g & 1) << 2);
#pragma unroll
    for (int kc = 0; kc < 2; ++kc)
        roff[kc] = c * 64 + (((4 * kc + g) ^ (c & 7)) << 3);
    unsigned short* L0 = &lds[wave][0][0];
    unsigned short* L1 = &lds[wave][1][0];

    const float* hrow = hist + (size_t)brow * SS * 8;
    float accO[8];
#pragma unroll
    for (int e = 0; e < 8; ++e) accO[e] = 0.0f;

    // preload subtiles 0,1 (row index clamped; overhang masked later)
    float hA[8], hB[8];
    {
        const float4* pa = reinterpret_cast<const float4*>(hrow + (size_t)min(c, SS - 1) * 8);
        const float4* pb = reinterpret_cast<const float4*>(hrow + (size_t)min(16 + c, SS - 1) * 8);
        float4 a0 = pa[0], a1 = pa[1], b0 = pb[0], b1_ = pb[1];
        hA[0]=a0.x; hA[1]=a0.y; hA[2]=a0.z; hA[3]=a0.w; hA[4]=a1.x; hA[5]=a1.y; hA[6]=a1.z; hA[7]=a1.w;
        hB[0]=b0.x; hB[1]=b0.y; hB[2]=b0.z; hB[3]=b0.w; hB[4]=b1_.x; hB[5]=b1_.y; hB[6]=b1_.z; hB[7]=b1_.w;
    }

#pragma unroll 1
    for (int it = 0; it < 7; ++it) {   // subtiles 2it, 2it+1 (13 real + 1 masked)
        // ---- prefetch next pair ----
        float nA[8], nB[8];
        if (it < 6) {
            const float4* pa = reinterpret_cast<const float4*>(hrow + (size_t)min(32 * it + 32 + c, SS - 1) * 8);
            const float4* pb = reinterpret_cast<const float4*>(hrow + (size_t)min(32 * it + 48 + c, SS - 1) * 8);
            float4 a0 = pa[0], a1 = pa[1], b0 = pb[0], b1_ = pb[1];
            nA[0]=a0.x; nA[1]=a0.y; nA[2]=a0.z; nA[3]=a0.w; nA[4]=a1.x; nA[5]=a1.y; nA[6]=a1.z; nA[7]=a1.w;
            nB[0]=b0.x; nB[1]=b0.y; nB[2]=b0.z; nB[3]=b0.w; nB[4]=b1_.x; nB[5]=b1_.y; nB[6]=b1_.z; nB[7]=b1_.w;
        }

        // ---- A-frags (B-role: att^T) ----
        union { unsigned int u[4]; short8 s; } ufA, ufB;
#pragma unroll
        for (int m = 0; m < 4; ++m) {
            ufA.u[m] = packbf2(fmaf(bcv[2*m], hA[2*m], aq[2*m]), fmaf(bcv[2*m+1], hA[2*m+1], aq[2*m+1]));
            ufB.u[m] = packbf2(fmaf(bcv[2*m], hB[2*m], aq[2*m]), fmaf(bcv[2*m+1], hB[2*m+1], aq[2*m+1]));
        }

        // ---- stage 1': h1^T tiles = W1^T @ att^T  (bias via C-operand) ----
        f32x4 a1A[4], a1B[4];
#pragma unroll
        for (int n = 0; n < 4; ++n) {
            a1A[n] = __builtin_amdgcn_mfma_f32_16x16x32_bf16(w1f[n], ufA.s, b1c[n], 0, 0, 0);
            a1B[n] = __builtin_amdgcn_mfma_f32_16x16x32_bf16(w1f[n], ufB.s, b1c[n], 0, 0, 0);
        }

        // ---- relu + pack + swizzled b64 writes (lane holds h1[c][16n+4g+r]) ----
#pragma unroll
        for (int n = 0; n < 4; ++n) {
            uint2 vA = make_uint2(packbf2(fmaxf(a1A[n][0], 0.f), fmaxf(a1A[n][1], 0.f)),
                                  packbf2(fmaxf(a1A[n][2], 0.f), fmaxf(a1A[n][3], 0.f)));
            uint2 vB = make_uint2(packbf2(fmaxf(a1B[n][0], 0.f), fmaxf(a1B[n][1], 0.f)),
                                  packbf2(fmaxf(a1B[n][2], 0.f), fmaxf(a1B[n][3], 0.f)));
            *reinterpret_cast<uint2*>(L0 + woff[n]) = vA;
            *reinterpret_cast<uint2*>(L1 + woff[n]) = vB;
        }

        asm volatile("s_waitcnt lgkmcnt(0)" ::: "memory");   // wave-local drain

        short8 hbA[2], hbB[2];
#pragma unroll
        for (int kc = 0; kc < 2; ++kc) {
            hbA[kc] = *reinterpret_cast<const short8*>(L0 + roff[kc]);
            hbB[kc] = *reinterpret_cast<const short8*>(L1 + roff[kc]);
        }

        // ---- stage 2': h2^T tiles = W2^T @ relu(h1)^T (bias via C-operand) ----
        f32x4 a2A[2], a2B[2];
#pragma unroll
        for (int n2 = 0; n2 < 2; ++n2) {
            a2A[n2] = __builtin_amdgcn_mfma_f32_16x16x32_bf16(w2tf[0][n2], hbA[0], b2c[n2], 0, 0, 0);
            a2A[n2] = __builtin_amdgcn_mfma_f32_16x16x32_bf16(w2tf[1][n2], hbA[1], a2A[n2], 0, 0, 0);
            a2B[n2] = __builtin_amdgcn_mfma_f32_16x16x32_bf16(w2tf[0][n2], hbB[0], b2c[n2], 0, 0, 0);
            a2B[n2] = __builtin_amdgcn_mfma_f32_16x16x32_bf16(w2tf[1][n2], hbB[1], a2B[n2], 0, 0, 0);
        }

        // ---- stage 3: lane-local partial dot with W3, then 2-hop butterfly ----
        float pA = 0.f, pB = 0.f;
#pragma unroll
        for (int n2 = 0; n2 < 2; ++n2)
#pragma unroll
            for (int r = 0; r < 4; ++r) {
                pA = fmaf(fmaxf(a2A[n2][r], 0.f), W3v[n2][r], pA);
                pB = fmaf(fmaxf(a2B[n2][r], 0.f), W3v[n2][r], pB);
            }
        pA += __shfl_xor(pA, 16); pA += __shfl_xor(pA, 32);
        pB += __shfl_xor(pB, 16); pB += __shfl_xor(pB, 32);

        const int s0 = 32 * it;
        float scA = (s0 + c      < len) ? (pA + b3s) : 0.0f;
        float scB = (s0 + 16 + c < len) ? (pB + b3s) : 0.0f;

        // ---- pooling (h fp32 already in the right lanes) ----
#pragma unroll
        for (int e = 0; e < 8; ++e) {
            accO[e] = fmaf(scA, hA[e], accO[e]);
            accO[e] = fmaf(scB, hB[e], accO[e]);
        }

        if (it < 6) {
#pragma unroll
            for (int j = 0; j < 8; ++j) { hA[j] = nA[j]; hB[j] = nB[j]; }
        }
    }

    // ---- final: sum over the 16 position-lanes (g-copies are identical) ----
#pragma unroll
    for (int m = 1; m < 16; m <<= 1)
#pragma unroll
        for (int e = 0; e < 8; ++e) accO[e] += __shfl_xor(accO[e], m);

    if (l == 0) {
        float4* op = reinterpret_cast<float4*>(out + (size_t)brow * 8);
        op[0] = make_float4(accO[0], accO[1], accO[2], accO[3]);
        op[1] = make_float4(accO[4], accO[5], accO[6], accO[7]);
    }
}

extern "C" void kernel_launch(void* const* d_in, const int* in_sizes, int n_in,
                              void* d_out, int out_size, void* d_ws, size_t ws_size,
                              hipStream_t stream) {
    const float* query = (const float*)d_in[0];
    const float* hist  = (const float*)d_in[1];
    const int*   hlen  = (const int*)d_in[2];
    const float* W1    = (const float*)d_in[3];
    const float* b1    = (const float*)d_in[4];
    const float* W2    = (const float*)d_in[5];
    const float* b2    = (const float*)d_in[6];
    const float* W3    = (const float*)d_in[7];
    const float* b3    = (const float*)d_in[8];
    float*       out   = (float*)d_out;

    unsigned short* wsW1 = (unsigned short*)d_ws;          // 4KB
    unsigned short* wsW2 = wsW1 + 4 * 64 * 8;              // 4KB

    prep_kernel<<<1, 256, 0, stream>>>(W1, W2, wsW1, wsW2);
    din2_kernel<<<BB / 4, 256, 0, stream>>>(query, hist, hlen, wsW1, wsW2,
                                            b1, b2, W3, b3, out);
}